// Round 17
// baseline (397.107 us; speedup 1.0000x reference)
//
#include <hip/hip_runtime.h>
#include <stdint.h>

#define D_MODEL 2048
#define NH 16
#define DH 128
#define BATCH 4
#define SEQ 2048
#define MTOT (BATCH*SEQ)   // 8192
#define LDQ 6144           // fused QKV row stride

typedef __bf16 bf16x8 __attribute__((ext_vector_type(8)));
typedef float f32x4 __attribute__((ext_vector_type(4)));
typedef short short8 __attribute__((ext_vector_type(8)));

static __device__ __forceinline__ unsigned short f2bf(float f) {
  union { float f; unsigned int u; } v; v.f = f;
  return (unsigned short)((v.u + 0x7FFFu + ((v.u >> 16) & 1u)) >> 16);
}

#define FENCEM() asm volatile("" ::: "memory")
#define GBAR() do { FENCEM(); __builtin_amdgcn_s_barrier(); FENCEM(); } while (0)

// ---------------- fused fp32 -> bf16 conversion (x + 4 weights, one dispatch) ----------------
// flat grid 16384 blocks: id<8192 -> x (16.7M elems); else weight (id-8192)>>11, 2048 blocks each.
__global__ __launch_bounds__(256) void cvt_all_k(const float* __restrict__ x,
                                                 const float* __restrict__ w0, const float* __restrict__ w1,
                                                 const float* __restrict__ w2, const float* __restrict__ w3,
                                                 unsigned short* __restrict__ xo,
                                                 unsigned short* __restrict__ wo_cat,
                                                 unsigned short* __restrict__ wo_o) {
  const size_t WSZ = (size_t)D_MODEL * D_MODEL;
  int id = blockIdx.x;
  const float* src; unsigned short* dst; int lo;
  if (id < 8192) { src = x; dst = xo; lo = id; }
  else {
    int wsel = (id - 8192) >> 11;
    lo = (id - 8192) & 2047;
    switch (wsel) {
      case 0: src = w0; dst = wo_cat; break;
      case 1: src = w1; dst = wo_cat + WSZ; break;
      case 2: src = w2; dst = wo_cat + 2 * WSZ; break;
      default: src = w3; dst = wo_o; break;
    }
  }
  int i = (lo * 256 + threadIdx.x) * 8;
  float4 a = *(const float4*)(src + i);
  float4 b = *(const float4*)(src + i + 4);
  union { unsigned short u[8]; short8 v; } o;
  o.u[0] = f2bf(a.x); o.u[1] = f2bf(a.y); o.u[2] = f2bf(a.z); o.u[3] = f2bf(a.w);
  o.u[4] = f2bf(b.x); o.u[5] = f2bf(b.y); o.u[6] = f2bf(b.z); o.u[7] = f2bf(b.w);
  *(short8*)(dst + i) = o.v;
}

// ---------------- 256x256 GEMM, SINGLE-buffer LDS (64KB) -> 2 blocks/CU ----------------
// Same BK=64, 2-barrier/K-tile, read patterns, stage protocol and 2D-slab XCD map as
// the r12-verified kernel; only the double-buffer is dropped. Sync per K-tile:
//   region 1: all tile-t LDS reads (af h0, bf0, bf1) + MFMA h0; LDA h1;
//   lgkmcnt(0)+GBAR  = ALL waves' reads of tile t complete (af, bf, af-h1);
//   region 2: stage tile t+1 into the SAME buffers (dead by WAR fence) + MFMA h1;
//   vmcnt(0)+GBAR    = staged tile landed & visible (full drain; cover ~ half tile,
//                      and the co-resident block hides the drain).
// launch_bounds stays (512,2): VGPR 116 already permits 4 waves/SIMD (r10 lesson:
// never tighten min-waves). r13 lesson respected: MFMA-per-barrier unchanged (64/tile).
template<bool OUT_BF16, bool ADD_BIAS>
__global__ __launch_bounds__(512, 2) void gemm256(const unsigned short* __restrict__ A,
                                                  const unsigned short* __restrict__ B,
                                                  void* __restrict__ C,
                                                  const float* __restrict__ bias,
                                                  int M, int N, int K) {
  __shared__ __align__(16) unsigned short As[256 * 64];   // 32KB
  __shared__ __align__(16) unsigned short Bs[256 * 64];   // 32KB

  const int tid = threadIdx.x;
  const int lane = tid & 63;
  const int l15 = lane & 15, l4 = lane >> 4;
  const int wid = tid >> 6;
  const int wr = wid >> 2, wc = wid & 3;    // 2 x 4 wave grid

  const int gx = gridDim.x;
  const int id = blockIdx.y * gx + blockIdx.x;
  const int msl = gx >> 2;                  // M-slab width (blocks)
  const int nsl = gridDim.y >> 1;           // N-slab width (blocks)
  const int xcd = id & 7;
  const int lid = id >> 3;
  const int bm = (xcd >> 1) * msl + lid / nsl;
  const int bn = (xcd & 1) * nsl + lid % nsl;

  const int NT = K >> 6;

  const int st_r = tid >> 3;
  const int st_c = (tid & 7) ^ (st_r & 7);
  const int st_ld = st_r * 64 + (tid & 7) * 8;

#define STAGE_A(t, h) do { \
  _Pragma("unroll") \
  for (int _i = 0; _i < 2; ++_i) { \
    const unsigned short* _g = A + (size_t)(bm * 256 + (h) * 128 + _i * 64 + st_r) * K + (t) * 64 + st_c * 8; \
    __builtin_amdgcn_global_load_lds((const __attribute__((address_space(1))) void*)_g, \
        (__attribute__((address_space(3))) void*)(&As[(h) * 8192 + _i * 4096 + st_ld]), 16, 0, 0); \
  } \
} while (0)

#define STAGE_B(t, h) do { \
  _Pragma("unroll") \
  for (int _i = 0; _i < 2; ++_i) { \
    const unsigned short* _g = B + (size_t)(bn * 256 + (h) * 128 + _i * 64 + st_r) * K + (t) * 64 + st_c * 8; \
    __builtin_amdgcn_global_load_lds((const __attribute__((address_space(1))) void*)_g, \
        (__attribute__((address_space(3))) void*)(&Bs[(h) * 8192 + _i * 4096 + st_ld]), 16, 0, 0); \
  } \
} while (0)

#define LDA_F(dst, mh) do { \
  _Pragma("unroll") \
  for (int _mi = 0; _mi < 4; ++_mi) { \
    int _row = wr * 128 + (mh) * 64 + _mi * 16 + l15; \
    _Pragma("unroll") \
    for (int _kk = 0; _kk < 2; ++_kk) \
      dst[_mi][_kk] = *(const bf16x8*)&As[_row * 64 + ((_kk * 4 + l4) ^ (l15 & 7)) * 8]; \
  } \
} while (0)

#define LDB_F(dst, nq) do { \
  _Pragma("unroll") \
  for (int _ni = 0; _ni < 2; ++_ni) { \
    int _row = wc * 64 + (nq) * 32 + _ni * 16 + l15; \
    _Pragma("unroll") \
    for (int _kk = 0; _kk < 2; ++_kk) \
      dst[_ni][_kk] = *(const bf16x8*)&Bs[_row * 64 + ((_kk * 4 + l4) ^ (l15 & 7)) * 8]; \
  } \
} while (0)

#define PHASE_MFMA(MH, NQ, BFR) do { \
  _Pragma("unroll") \
  for (int _mi = 0; _mi < 4; ++_mi) { \
    _Pragma("unroll") \
    for (int _ni = 0; _ni < 2; ++_ni) { \
      acc[(MH) * 4 + _mi][(NQ) * 2 + _ni] = __builtin_amdgcn_mfma_f32_16x16x32_bf16( \
          af[_mi][0], BFR[_ni][0], acc[(MH) * 4 + _mi][(NQ) * 2 + _ni], 0, 0, 0); \
      acc[(MH) * 4 + _mi][(NQ) * 2 + _ni] = __builtin_amdgcn_mfma_f32_16x16x32_bf16( \
          af[_mi][1], BFR[_ni][1], acc[(MH) * 4 + _mi][(NQ) * 2 + _ni], 0, 0, 0); \
    } \
  } \
} while (0)

  f32x4 acc[8][4] = {};

  // prologue: stage tile 0 (A+B), full drain, barrier
  STAGE_A(0, 0); STAGE_A(0, 1);
  STAGE_B(0, 0); STAGE_B(0, 1);
  asm volatile("s_waitcnt vmcnt(0)" ::: "memory");
  GBAR();

  for (int t = 0; t < NT; ++t) {
    bf16x8 af[4][2], bf0[2][2], bf1[2][2];

    // ---- region 1: all B-frags + A m-half0; MFMA half0 ----
    LDA_F(af, 0);
    LDB_F(bf0, 0);
    LDB_F(bf1, 1);
    __builtin_amdgcn_s_setprio(1);
    PHASE_MFMA(0, 0, bf0);
    PHASE_MFMA(0, 1, bf1);
    __builtin_amdgcn_s_setprio(0);

    // A m-half1 reads (same buffer, read-only)
    LDA_F(af, 1);
    asm volatile("s_waitcnt lgkmcnt(0)" ::: "memory");   // all my LDS reads of tile t done
    GBAR();                                              // WAR: ALL waves' reads done

    // ---- region 2: stage tile t+1 into the now-dead buffers; MFMA half1 ----
    if (t + 1 < NT) { STAGE_A(t + 1, 0); STAGE_A(t + 1, 1);
                      STAGE_B(t + 1, 0); STAGE_B(t + 1, 1); }
    __builtin_amdgcn_s_setprio(1);
    PHASE_MFMA(1, 1, bf1);
    PHASE_MFMA(1, 0, bf0);
    __builtin_amdgcn_s_setprio(0);
    asm volatile("s_waitcnt vmcnt(0)" ::: "memory");     // staged tile landed
    GBAR();                                              // visible to all waves
  }

  const int row0 = bm * 256 + wr * 128;
  const int col0 = bn * 256 + wc * 64;
#pragma unroll
  for (int mi = 0; mi < 8; ++mi) {
#pragma unroll
    for (int ni = 0; ni < 4; ++ni) {
      int col = col0 + ni * 16 + l15;
#pragma unroll
      for (int r = 0; r < 4; ++r) {
        int row = row0 + mi * 16 + l4 * 4 + r;
        float v = acc[mi][ni][r];
        if (ADD_BIAS) v += bias[col];
        if (OUT_BF16)
          ((unsigned short*)C)[(size_t)row * N + col] = f2bf(v);
        else
          ((float*)C)[(size_t)row * N + col] = v;
      }
    }
  }
#undef STAGE_A
#undef STAGE_B
#undef LDA_F
#undef LDB_F
#undef PHASE_MFMA
}

// ---------------- causal flash attention, counted-vmcnt pipeline (r12 verified) ----------------
__global__ __launch_bounds__(256, 2) void attn_k(const unsigned short* __restrict__ Qp,
                                                 const unsigned short* __restrict__ Kp,
                                                 const unsigned short* __restrict__ Vp,
                                                 unsigned short* __restrict__ O) {
  __shared__ __align__(16) unsigned short Ks[2][64 * 128];   // 32KB dbuf
  __shared__ __align__(16) unsigned short Vt[2][128 * 64];   // 32KB dbuf, [dh][key]
  __shared__ __align__(16) unsigned int   Pl[4][32 * 32];    // 16KB per-wave P

  const int tid = threadIdx.x;
  const int lane = tid & 63;
  const int l15 = lane & 15, l4 = lane >> 4;
  const int w = tid >> 6;

  const int idx = blockIdx.y * gridDim.x + blockIdx.x;
  const int x8 = idx & 7, j = idx >> 3;
  const int bh = x8 * 8 + (j & 7);
  const int qt = 15 - (j >> 3);              // heavy blocks dispatched first
  const int b = bh >> 4, h = bh & 15;

  const size_t baseI = (size_t)b * SEQ * LDQ + (size_t)h * DH;
  const size_t baseO = (size_t)b * SEQ * D_MODEL + (size_t)h * DH;
  const int qw = qt * 128 + w * 32;

  bf16x8 qf[2][4];
#pragma unroll
  for (int qg = 0; qg < 2; ++qg) {
    const unsigned short* qptr = Qp + baseI + (size_t)(qw + qg * 16 + l15) * LDQ;
#pragma unroll
    for (int kk = 0; kk < 4; ++kk)
      qf[qg][kk] = *(const bf16x8*)(qptr + kk * 32 + l4 * 8);
  }

  f32x4 acc[2][8] = {};
  float m_run[2] = {-3.4028235e38f, -3.4028235e38f};
  float lp[2] = {0.f, 0.f};
  const float SC = 0.12751743f;  // (1/sqrt(128)) * log2(e)

  short8 vreg[4];
  const int nkt = 2 * qt + 2;

  const int vkp0 = tid >> 4, vch0 = tid & 15;
  const int vkp1 = (tid + 256) >> 4, vch1 = vch0;

  // ---- prologue: stage kt=0 (K glds first, then V loads — vmcnt FIFO discipline) ----
#pragma unroll
  for (int it = 0; it < 4; ++it) {
    int c = tid + it * 256;
    int key = c >> 4, pos = c & 15;
    int gchunk = pos ^ (key & 7);
    const unsigned short* ga = Kp + baseI + (size_t)key * LDQ + gchunk * 8;
    __builtin_amdgcn_global_load_lds((const __attribute__((address_space(1))) void*)ga,
                                     (__attribute__((address_space(3))) void*)(&Ks[0][c * 8]),
                                     16, 0, 0);
  }
  FENCEM();
  {
    const unsigned short* gv0 = Vp + baseI + (size_t)(2 * vkp0) * LDQ + vch0 * 8;
    vreg[0] = *(const short8*)(gv0);
    vreg[1] = *(const short8*)(gv0 + LDQ);
    const unsigned short* gv1 = Vp + baseI + (size_t)(2 * vkp1) * LDQ + vch1 * 8;
    vreg[2] = *(const short8*)(gv1);
    vreg[3] = *(const short8*)(gv1 + LDQ);
  }

  for (int kt = 0; kt < nkt; ++kt) {
    const int cur = kt & 1;
    const int kv0 = kt * 64;
    const bool act = (kv0 <= qw + 31);

    // K(kt) glds landed (4 newest = this tile's V loads may still fly)
    asm volatile("s_waitcnt vmcnt(4)" ::: "memory");
    GBAR();                                   // everyone's K share landed -> Ks[cur] complete

    // ---- S^T = K Q^T (V loads still in flight underneath) ----
    f32x4 sacc[2][4] = {};
    if (act) {
      __builtin_amdgcn_s_setprio(1);
#pragma unroll
      for (int st = 0; st < 4; ++st) {
        int key = st * 16 + l15;
#pragma unroll
        for (int kk = 0; kk < 4; ++kk) {
          bf16x8 kf = *(const bf16x8*)&Ks[cur][key * 128 + ((kk * 32 + l4 * 8) ^ ((key & 7) << 3))];
          sacc[0][st] = __builtin_amdgcn_mfma_f32_16x16x32_bf16(kf, qf[0][kk], sacc[0][st], 0, 0, 0);
          sacc[1][st] = __builtin_amdgcn_mfma_f32_16x16x32_bf16(kf, qf[1][kk], sacc[1][st], 0, 0, 0);
        }
      }
      __builtin_amdgcn_s_setprio(0);
    }
    FENCEM();

    // issue next tile's K glds (into the other K buffer; unread until next barrier)
    if (kt + 1 < nkt) {
      const int kn0 = kv0 + 64;
      const int nb = cur ^ 1;
#pragma unroll
      for (int it = 0; it < 4; ++it) {
        int c = tid + it * 256;
        int key = c >> 4, pos = c & 15;
        int gchunk = pos ^ (key & 7);
        const unsigned short* ga = Kp + baseI + (size_t)(kn0 + key) * LDQ + gchunk * 8;
        __builtin_amdgcn_global_load_lds((const __attribute__((address_space(1))) void*)ga,
                                         (__attribute__((address_space(3))) void*)(&Ks[nb][c * 8]),
                                         16, 0, 0);
      }
      asm volatile("s_waitcnt vmcnt(4)" ::: "memory");   // V(kt) landed; K(kt+1) in flight
    } else {
      asm volatile("s_waitcnt vmcnt(0)" ::: "memory");   // last tile: drain V(kt)
    }

    // scatter V(kt) regs -> Vt[cur] (paired b32 writes, verified layout)
#pragma unroll
    for (int i = 0; i < 2; ++i) {
      int kp = i ? vkp1 : vkp0;
      int ch = i ? vch1 : vch0;
      union { short8 v; unsigned short u[8]; } ua, ub;
      ua.v = vreg[2 * i]; ub.v = vreg[2 * i + 1];
#pragma unroll
      for (int j2 = 0; j2 < 8; ++j2) {
        int dh = ch * 8 + j2;
        int sv = (ch ^ j2) & 7;
        unsigned val = (unsigned)ua.u[j2] | ((unsigned)ub.u[j2] << 16);
        *(unsigned int*)&Vt[cur][dh * 64 + ((2 * kp) ^ (sv << 3))] = val;
      }
    }
    // issue next tile's V loads (after scatter consumed vreg — register anti-dep)
    if (kt + 1 < nkt) {
      const int kn0 = kv0 + 64;
      const unsigned short* gv0 = Vp + baseI + (size_t)(kn0 + 2 * vkp0) * LDQ + vch0 * 8;
      vreg[0] = *(const short8*)(gv0);
      vreg[1] = *(const short8*)(gv0 + LDQ);
      const unsigned short* gv1 = Vp + baseI + (size_t)(kn0 + 2 * vkp1) * LDQ + vch1 * 8;
      vreg[2] = *(const short8*)(gv1);
      vreg[3] = *(const short8*)(gv1 + LDQ);
    }
    __syncthreads();   // Vt[cur] visible (includes lgkmcnt drain of scatter)

    if (act) {
      // ---- online softmax (defer-max THR=8) ----
      const bool tail = (kv0 + 63 > qw);
      float tmax[2];
#pragma unroll
      for (int qg = 0; qg < 2; ++qg) {
        if (tail) {
          int q = qw + qg * 16 + l15;
#pragma unroll
          for (int st = 0; st < 4; ++st)
#pragma unroll
            for (int r = 0; r < 4; ++r) {
              int key = kv0 + st * 16 + l4 * 4 + r;
              if (key > q) sacc[qg][st][r] = -3.0e38f;
            }
        }
        float a0 = fmaxf(fmaxf(sacc[qg][0][0], sacc[qg][0][1]), fmaxf(sacc[qg][0][2], sacc[qg][0][3]));
        float a1 = fmaxf(fmaxf(sacc[qg][1][0], sacc[qg][1][1]), fmaxf(sacc[qg][1][2], sacc[qg][1][3]));
        float a2 = fmaxf(fmaxf(sacc[qg][2][0], sacc[qg][2][1]), fmaxf(sacc[qg][2][2], sacc[qg][2][3]));
        float a3 = fmaxf(fmaxf(sacc[qg][3][0], sacc[qg][3][1]), fmaxf(sacc[qg][3][2], sacc[qg][3][3]));
        float t = fmaxf(fmaxf(a0, a1), fmaxf(a2, a3));
        t = fmaxf(t, __shfl_xor(t, 16));
        t = fmaxf(t, __shfl_xor(t, 32));
        tmax[qg] = t;
      }
      bool grow = (tmax[0] > m_run[0] + 8.f) || (tmax[1] > m_run[1] + 8.f);
      if (__any(grow)) {
#pragma unroll
        for (int qg = 0; qg < 2; ++qg) {
          float nm = fmaxf(m_run[qg], tmax[qg]);
          float scl = __builtin_amdgcn_exp2f((m_run[qg] - nm) * SC);
          m_run[qg] = nm;
          lp[qg] *= scl;
#pragma unroll
          for (int r = 0; r < 4; ++r) {
            float srow = __shfl(scl, l4 * 4 + r);
#pragma unroll
            for (int df = 0; df < 8; ++df) acc[qg][df][r] *= srow;
          }
        }
      }
#pragma unroll
      for (int qg = 0; qg < 2; ++qg) {
        int q = qg * 16 + l15;
        float ps = 0.f;
#pragma unroll
        for (int st = 0; st < 4; ++st) {
          float p0 = __builtin_amdgcn_exp2f((sacc[qg][st][0] - m_run[qg]) * SC);
          float p1 = __builtin_amdgcn_exp2f((sacc[qg][st][1] - m_run[qg]) * SC);
          float p2 = __builtin_amdgcn_exp2f((sacc[qg][st][2] - m_run[qg]) * SC);
          float p3 = __builtin_amdgcn_exp2f((sacc[qg][st][3] - m_run[qg]) * SC);
          ps += (p0 + p1) + (p2 + p3);
          unsigned w0 = (unsigned)f2bf(p0) | ((unsigned)f2bf(p1) << 16);
          unsigned w1 = (unsigned)f2bf(p2) | ((unsigned)f2bf(p3) << 16);
          int kw0 = st * 8 + l4 * 2;
          Pl[w][q * 32 + (kw0 ^ ((q & 7) << 2))] = w0;
          Pl[w][q * 32 + ((kw0 + 1) ^ ((q & 7) << 2))] = w1;
        }
        lp[qg] += ps;
      }
      // ---- O += P V ----
      __builtin_amdgcn_s_setprio(1);
#pragma unroll
      for (int ks2 = 0; ks2 < 2; ++ks2) {
        int kwb = ks2 * 16 + l4 * 4;
        bf16x8 pa0 = *(const bf16x8*)&Pl[w][l15 * 32 + (kwb ^ ((l15 & 7) << 2))];
        bf16x8 pa1 = *(const bf16x8*)&Pl[w][(16 + l15) * 32 + (kwb ^ ((l15 & 7) << 2))];
#pragma unroll
        for (int df = 0; df < 8; ++df) {
          int dh = df * 16 + l15;
          int sv = ((dh >> 3) ^ dh) & 7;
          bf16x8 vb = *(const bf16x8*)&Vt[cur][dh * 64 + ((ks2 * 32 + l4 * 8) ^ (sv << 3))];
          acc[0][df] = __builtin_amdgcn_mfma_f32_16x16x32_bf16(pa0, vb, acc[0][df], 0, 0, 0);
          acc[1][df] = __builtin_amdgcn_mfma_f32_16x16x32_bf16(pa1, vb, acc[1][df], 0, 0, 0);
        }
      }
      __builtin_amdgcn_s_setprio(0);
    }
  }

#pragma unroll
  for (int qg = 0; qg < 2; ++qg) {
    float t = lp[qg];
    t += __shfl_xor(t, 16);
    t += __shfl_xor(t, 32);
    float linv = 1.0f / t;
#pragma unroll
    for (int r = 0; r < 4; ++r) {
      float lrow = __shfl(linv, l4 * 4 + r);
      int row = qw + qg * 16 + l4 * 4 + r;
#pragma unroll
      for (int df = 0; df < 8; ++df)
        O[baseO + (size_t)row * D_MODEL + df * 16 + l15] = f2bf(acc[qg][df][r] * lrow);
    }
  }
}

// ---------------- launch ----------------
extern "C" void kernel_launch(void* const* d_in, const int* in_sizes, int n_in,
                              void* d_out, int out_size, void* d_ws, size_t ws_size,
                              hipStream_t stream) {
  const float* x  = (const float*)d_in[0];
  const float* Wq = (const float*)d_in[1];
  const float* Wk = (const float*)d_in[2];
  const float* Wv = (const float*)d_in[3];
  const float* Wo = (const float*)d_in[4];
  const float* bo = (const float*)d_in[5];
  float* out = (float*)d_out;

  unsigned short* ws = (unsigned short*)d_ws;
  const size_t XSZ = (size_t)MTOT * D_MODEL;      // 16,777,216
  const size_t WSZ = (size_t)D_MODEL * D_MODEL;   // 4,194,304
  unsigned short* xb   = ws;                       // also reused as attn-out
  unsigned short* Wcat = xb + XSZ;                 // [6144][2048] = Wq|Wk|Wv rows
  unsigned short* Wob  = Wcat + 3 * WSZ;
  unsigned short* QKV  = Wob + WSZ;                // [8192][6144]
  unsigned short* AOb  = xb;

  // fused conversions: x (8192 blocks) + 4 weights (2048 each) = 16384 blocks
  cvt_all_k<<<16384, 256, 0, stream>>>(x, Wq, Wk, Wv, Wo, xb, Wcat, Wob);

  // fused QKV projection: [8192,2048] x [6144,2048]^T -> [8192,6144]
  dim3 gq(MTOT / 256, LDQ / 256);   // 32 x 24 = 768 blocks
  gemm256<true, false><<<gq, 512, 0, stream>>>(xb, Wcat, QKV, nullptr, MTOT, LDQ, D_MODEL);

  dim3 ga(SEQ / 128, BATCH * NH);   // 16 x 64
  attn_k<<<ga, 256, 0, stream>>>(QKV, QKV + 2048, QKV + 4096, AOb);

  // output projection: [8192,2048] x [2048,2048]^T -> fp32 + bias
  dim3 gg(MTOT / 256, D_MODEL / 256);  // 32 x 8 = 256 blocks
  gemm256<false, true><<<gg, 512, 0, stream>>>(AOb, Wob, out, bo, MTOT, D_MODEL, D_MODEL);
}

// Round 18
// 387.751 us; speedup vs baseline: 1.0241x; 1.0241x over previous
//
#include <hip/hip_runtime.h>
#include <stdint.h>

#define D_MODEL 2048
#define NH 16
#define DH 128
#define BATCH 4
#define SEQ 2048
#define MTOT (BATCH*SEQ)   // 8192
#define LDQ 6144           // fused QKV row stride

typedef __bf16 bf16x8 __attribute__((ext_vector_type(8)));
typedef float f32x4 __attribute__((ext_vector_type(4)));
typedef short short8 __attribute__((ext_vector_type(8)));

static __device__ __forceinline__ unsigned short f2bf(float f) {
  union { float f; unsigned int u; } v; v.f = f;
  return (unsigned short)((v.u + 0x7FFFu + ((v.u >> 16) & 1u)) >> 16);
}

#define FENCEM() asm volatile("" ::: "memory")
#define GBAR() do { FENCEM(); __builtin_amdgcn_s_barrier(); FENCEM(); } while (0)

// ---------------- fused fp32 -> bf16 conversion (x + 4 weights, one dispatch) ----------------
__global__ __launch_bounds__(256) void cvt_all_k(const float* __restrict__ x,
                                                 const float* __restrict__ w0, const float* __restrict__ w1,
                                                 const float* __restrict__ w2, const float* __restrict__ w3,
                                                 unsigned short* __restrict__ xo,
                                                 unsigned short* __restrict__ wo_cat,
                                                 unsigned short* __restrict__ wo_o) {
  const size_t WSZ = (size_t)D_MODEL * D_MODEL;
  int id = blockIdx.x;
  const float* src; unsigned short* dst; int lo;
  if (id < 8192) { src = x; dst = xo; lo = id; }
  else {
    int wsel = (id - 8192) >> 11;
    lo = (id - 8192) & 2047;
    switch (wsel) {
      case 0: src = w0; dst = wo_cat; break;
      case 1: src = w1; dst = wo_cat + WSZ; break;
      case 2: src = w2; dst = wo_cat + 2 * WSZ; break;
      default: src = w3; dst = wo_o; break;
    }
  }
  int i = (lo * 256 + threadIdx.x) * 8;
  float4 a = *(const float4*)(src + i);
  float4 b = *(const float4*)(src + i + 4);
  union { unsigned short u[8]; short8 v; } o;
  o.u[0] = f2bf(a.x); o.u[1] = f2bf(a.y); o.u[2] = f2bf(a.z); o.u[3] = f2bf(a.w);
  o.u[4] = f2bf(b.x); o.u[5] = f2bf(b.y); o.u[6] = f2bf(b.z); o.u[7] = f2bf(b.w);
  *(short8*)(dst + i) = o.v;
}

// ---------------- 256x256 GEMM, 2-barrier/K-tile, 2D-slab XCD mapping ----------------
// EXACT r12-verified schedule (190us, MfmaUtil 48.6%, 0 conflicts, 116 VGPR).
// Structure exploration closed: 7 variants (4-phase 39%, BK=32 40%, region-2-B 45.7%,
// single-buf 45.4%, af2-early 47.6%, B-hold 48.6%, direct-B catastrophic) bracket
// this as the template optimum.
template<bool OUT_BF16, bool ADD_BIAS>
__global__ __launch_bounds__(512, 2) void gemm256(const unsigned short* __restrict__ A,
                                                  const unsigned short* __restrict__ B,
                                                  void* __restrict__ C,
                                                  const float* __restrict__ bias,
                                                  int M, int N, int K) {
  __shared__ __align__(16) unsigned short As[2][256 * 64];   // 64KB
  __shared__ __align__(16) unsigned short Bs[2][256 * 64];   // 64KB

  const int tid = threadIdx.x;
  const int lane = tid & 63;
  const int l15 = lane & 15, l4 = lane >> 4;
  const int wid = tid >> 6;
  const int wr = wid >> 2, wc = wid & 3;    // 2 x 4 wave grid

  const int gx = gridDim.x;
  const int id = blockIdx.y * gx + blockIdx.x;
  const int msl = gx >> 2;                  // M-slab width (blocks)
  const int nsl = gridDim.y >> 1;           // N-slab width (blocks)
  const int xcd = id & 7;
  const int lid = id >> 3;
  const int bm = (xcd >> 1) * msl + lid / nsl;
  const int bn = (xcd & 1) * nsl + lid % nsl;

  const int NT = K >> 6;

  const int st_r = tid >> 3;
  const int st_c = (tid & 7) ^ (st_r & 7);
  const int st_ld = st_r * 64 + (tid & 7) * 8;

#define STAGE_A(t, h) do { \
  const int _b = (t) & 1; \
  _Pragma("unroll") \
  for (int _i = 0; _i < 2; ++_i) { \
    const unsigned short* _g = A + (size_t)(bm * 256 + (h) * 128 + _i * 64 + st_r) * K + (t) * 64 + st_c * 8; \
    __builtin_amdgcn_global_load_lds((const __attribute__((address_space(1))) void*)_g, \
        (__attribute__((address_space(3))) void*)(&As[_b][(h) * 8192 + _i * 4096 + st_ld]), 16, 0, 0); \
  } \
} while (0)

#define STAGE_B(t, h) do { \
  const int _b = (t) & 1; \
  _Pragma("unroll") \
  for (int _i = 0; _i < 2; ++_i) { \
    const unsigned short* _g = B + (size_t)(bn * 256 + (h) * 128 + _i * 64 + st_r) * K + (t) * 64 + st_c * 8; \
    __builtin_amdgcn_global_load_lds((const __attribute__((address_space(1))) void*)_g, \
        (__attribute__((address_space(3))) void*)(&Bs[_b][(h) * 8192 + _i * 4096 + st_ld]), 16, 0, 0); \
  } \
} while (0)

#define LDA_F(dst, bufb, mh) do { \
  _Pragma("unroll") \
  for (int _mi = 0; _mi < 4; ++_mi) { \
    int _row = wr * 128 + (mh) * 64 + _mi * 16 + l15; \
    _Pragma("unroll") \
    for (int _kk = 0; _kk < 2; ++_kk) \
      dst[_mi][_kk] = *(const bf16x8*)&As[bufb][_row * 64 + ((_kk * 4 + l4) ^ (l15 & 7)) * 8]; \
  } \
} while (0)

#define LDB_F(dst, bufb, nq) do { \
  _Pragma("unroll") \
  for (int _ni = 0; _ni < 2; ++_ni) { \
    int _row = wc * 64 + (nq) * 32 + _ni * 16 + l15; \
    _Pragma("unroll") \
    for (int _kk = 0; _kk < 2; ++_kk) \
      dst[_ni][_kk] = *(const bf16x8*)&Bs[bufb][_row * 64 + ((_kk * 4 + l4) ^ (l15 & 7)) * 8]; \
  } \
} while (0)

#define PHASE_MFMA(MH, NQ, BFR) do { \
  _Pragma("unroll") \
  for (int _mi = 0; _mi < 4; ++_mi) { \
    _Pragma("unroll") \
    for (int _ni = 0; _ni < 2; ++_ni) { \
      acc[(MH) * 4 + _mi][(NQ) * 2 + _ni] = __builtin_amdgcn_mfma_f32_16x16x32_bf16( \
          af[_mi][0], BFR[_ni][0], acc[(MH) * 4 + _mi][(NQ) * 2 + _ni], 0, 0, 0); \
      acc[(MH) * 4 + _mi][(NQ) * 2 + _ni] = __builtin_amdgcn_mfma_f32_16x16x32_bf16( \
          af[_mi][1], BFR[_ni][1], acc[(MH) * 4 + _mi][(NQ) * 2 + _ni], 0, 0, 0); \
    } \
  } \
} while (0)

  f32x4 acc[8][4] = {};

  STAGE_A(0, 0); STAGE_A(0, 1);
  STAGE_B(0, 0); STAGE_B(0, 1);
  if (NT > 1) { STAGE_A(1, 0); STAGE_A(1, 1); }
  if (NT > 1) asm volatile("s_waitcnt vmcnt(4)" ::: "memory");
  else        asm volatile("s_waitcnt vmcnt(0)" ::: "memory");
  GBAR();

  for (int t = 0; t < NT; ++t) {
    const int bufb = t & 1;
    bf16x8 af[4][2], bf0[2][2], bf1[2][2];

    // ---- region 1: all B-frags + A m-half0; stage B(t+1); MFMA half0 ----
    LDA_F(af, bufb, 0);
    LDB_F(bf0, bufb, 0);
    LDB_F(bf1, bufb, 1);
    if (t + 1 < NT) { STAGE_B(t + 1, 0); STAGE_B(t + 1, 1); }
    __builtin_amdgcn_s_setprio(1);
    PHASE_MFMA(0, 0, bf0);
    PHASE_MFMA(0, 1, bf1);
    __builtin_amdgcn_s_setprio(0);

    // A m-half1 reads (same buffer, read-only)
    LDA_F(af, bufb, 1);
    asm volatile("s_waitcnt lgkmcnt(0)" ::: "memory");   // my A-reads of buf t done
    GBAR();                                              // WAR: ALL waves' reads done

    // ---- region 2: stage A(t+2) into now-dead A buffer; MFMA half1 ----
    if (t + 2 < NT) { STAGE_A(t + 2, 0); STAGE_A(t + 2, 1); }
    __builtin_amdgcn_s_setprio(1);
    PHASE_MFMA(1, 1, bf1);
    PHASE_MFMA(1, 0, bf0);
    __builtin_amdgcn_s_setprio(0);
    if (t + 2 < NT) asm volatile("s_waitcnt vmcnt(4)" ::: "memory");
    else            asm volatile("s_waitcnt vmcnt(0)" ::: "memory");
    GBAR();   // tile boundary: A(t+1)+B(t+1) landed & visible; A(t+2) in flight
  }

  const int row0 = bm * 256 + wr * 128;
  const int col0 = bn * 256 + wc * 64;
#pragma unroll
  for (int mi = 0; mi < 8; ++mi) {
#pragma unroll
    for (int ni = 0; ni < 4; ++ni) {
      int col = col0 + ni * 16 + l15;
#pragma unroll
      for (int r = 0; r < 4; ++r) {
        int row = row0 + mi * 16 + l4 * 4 + r;
        float v = acc[mi][ni][r];
        if (ADD_BIAS) v += bias[col];
        if (OUT_BF16)
          ((unsigned short*)C)[(size_t)row * N + col] = f2bf(v);
        else
          ((float*)C)[(size_t)row * N + col] = v;
      }
    }
  }
#undef STAGE_A
#undef STAGE_B
#undef LDA_F
#undef LDB_F
#undef PHASE_MFMA
}

// ---------------- causal flash attention, counted-vmcnt pipeline (r12 verified) ----------------
__global__ __launch_bounds__(256, 2) void attn_k(const unsigned short* __restrict__ Qp,
                                                 const unsigned short* __restrict__ Kp,
                                                 const unsigned short* __restrict__ Vp,
                                                 unsigned short* __restrict__ O) {
  __shared__ __align__(16) unsigned short Ks[2][64 * 128];   // 32KB dbuf
  __shared__ __align__(16) unsigned short Vt[2][128 * 64];   // 32KB dbuf, [dh][key]
  __shared__ __align__(16) unsigned int   Pl[4][32 * 32];    // 16KB per-wave P

  const int tid = threadIdx.x;
  const int lane = tid & 63;
  const int l15 = lane & 15, l4 = lane >> 4;
  const int w = tid >> 6;

  const int idx = blockIdx.y * gridDim.x + blockIdx.x;
  const int x8 = idx & 7, j = idx >> 3;
  const int bh = x8 * 8 + (j & 7);
  const int qt = 15 - (j >> 3);              // heavy blocks dispatched first
  const int b = bh >> 4, h = bh & 15;

  const size_t baseI = (size_t)b * SEQ * LDQ + (size_t)h * DH;
  const size_t baseO = (size_t)b * SEQ * D_MODEL + (size_t)h * DH;
  const int qw = qt * 128 + w * 32;

  bf16x8 qf[2][4];
#pragma unroll
  for (int qg = 0; qg < 2; ++qg) {
    const unsigned short* qptr = Qp + baseI + (size_t)(qw + qg * 16 + l15) * LDQ;
#pragma unroll
    for (int kk = 0; kk < 4; ++kk)
      qf[qg][kk] = *(const bf16x8*)(qptr + kk * 32 + l4 * 8);
  }

  f32x4 acc[2][8] = {};
  float m_run[2] = {-3.4028235e38f, -3.4028235e38f};
  float lp[2] = {0.f, 0.f};
  const float SC = 0.12751743f;  // (1/sqrt(128)) * log2(e)

  short8 vreg[4];
  const int nkt = 2 * qt + 2;

  const int vkp0 = tid >> 4, vch0 = tid & 15;
  const int vkp1 = (tid + 256) >> 4, vch1 = vch0;

  // ---- prologue: stage kt=0 (K glds first, then V loads — vmcnt FIFO discipline) ----
#pragma unroll
  for (int it = 0; it < 4; ++it) {
    int c = tid + it * 256;
    int key = c >> 4, pos = c & 15;
    int gchunk = pos ^ (key & 7);
    const unsigned short* ga = Kp + baseI + (size_t)key * LDQ + gchunk * 8;
    __builtin_amdgcn_global_load_lds((const __attribute__((address_space(1))) void*)ga,
                                     (__attribute__((address_space(3))) void*)(&Ks[0][c * 8]),
                                     16, 0, 0);
  }
  FENCEM();
  {
    const unsigned short* gv0 = Vp + baseI + (size_t)(2 * vkp0) * LDQ + vch0 * 8;
    vreg[0] = *(const short8*)(gv0);
    vreg[1] = *(const short8*)(gv0 + LDQ);
    const unsigned short* gv1 = Vp + baseI + (size_t)(2 * vkp1) * LDQ + vch1 * 8;
    vreg[2] = *(const short8*)(gv1);
    vreg[3] = *(const short8*)(gv1 + LDQ);
  }

  for (int kt = 0; kt < nkt; ++kt) {
    const int cur = kt & 1;
    const int kv0 = kt * 64;
    const bool act = (kv0 <= qw + 31);

    // K(kt) glds landed (4 newest = this tile's V loads may still fly)
    asm volatile("s_waitcnt vmcnt(4)" ::: "memory");
    GBAR();                                   // everyone's K share landed -> Ks[cur] complete

    // ---- S^T = K Q^T (V loads still in flight underneath) ----
    f32x4 sacc[2][4] = {};
    if (act) {
      __builtin_amdgcn_s_setprio(1);
#pragma unroll
      for (int st = 0; st < 4; ++st) {
        int key = st * 16 + l15;
#pragma unroll
        for (int kk = 0; kk < 4; ++kk) {
          bf16x8 kf = *(const bf16x8*)&Ks[cur][key * 128 + ((kk * 32 + l4 * 8) ^ ((key & 7) << 3))];
          sacc[0][st] = __builtin_amdgcn_mfma_f32_16x16x32_bf16(kf, qf[0][kk], sacc[0][st], 0, 0, 0);
          sacc[1][st] = __builtin_amdgcn_mfma_f32_16x16x32_bf16(kf, qf[1][kk], sacc[1][st], 0, 0, 0);
        }
      }
      __builtin_amdgcn_s_setprio(0);
    }
    FENCEM();

    // issue next tile's K glds (into the other K buffer; unread until next barrier)
    if (kt + 1 < nkt) {
      const int kn0 = kv0 + 64;
      const int nb = cur ^ 1;
#pragma unroll
      for (int it = 0; it < 4; ++it) {
        int c = tid + it * 256;
        int key = c >> 4, pos = c & 15;
        int gchunk = pos ^ (key & 7);
        const unsigned short* ga = Kp + baseI + (size_t)(kn0 + key) * LDQ + gchunk * 8;
        __builtin_amdgcn_global_load_lds((const __attribute__((address_space(1))) void*)ga,
                                         (__attribute__((address_space(3))) void*)(&Ks[nb][c * 8]),
                                         16, 0, 0);
      }
      asm volatile("s_waitcnt vmcnt(4)" ::: "memory");   // V(kt) landed; K(kt+1) in flight
    } else {
      asm volatile("s_waitcnt vmcnt(0)" ::: "memory");   // last tile: drain V(kt)
    }

    // scatter V(kt) regs -> Vt[cur] (paired b32 writes, verified layout)
#pragma unroll
    for (int i = 0; i < 2; ++i) {
      int kp = i ? vkp1 : vkp0;
      int ch = i ? vch1 : vch0;
      union { short8 v; unsigned short u[8]; } ua, ub;
      ua.v = vreg[2 * i]; ub.v = vreg[2 * i + 1];
#pragma unroll
      for (int j2 = 0; j2 < 8; ++j2) {
        int dh = ch * 8 + j2;
        int sv = (ch ^ j2) & 7;
        unsigned val = (unsigned)ua.u[j2] | ((unsigned)ub.u[j2] << 16);
        *(unsigned int*)&Vt[cur][dh * 64 + ((2 * kp) ^ (sv << 3))] = val;
      }
    }
    // issue next tile's V loads (after scatter consumed vreg — register anti-dep)
    if (kt + 1 < nkt) {
      const int kn0 = kv0 + 64;
      const unsigned short* gv0 = Vp + baseI + (size_t)(kn0 + 2 * vkp0) * LDQ + vch0 * 8;
      vreg[0] = *(const short8*)(gv0);
      vreg[1] = *(const short8*)(gv0 + LDQ);
      const unsigned short* gv1 = Vp + baseI + (size_t)(kn0 + 2 * vkp1) * LDQ + vch1 * 8;
      vreg[2] = *(const short8*)(gv1);
      vreg[3] = *(const short8*)(gv1 + LDQ);
    }
    __syncthreads();   // Vt[cur] visible (includes lgkmcnt drain of scatter)

    if (act) {
      // ---- online softmax (defer-max THR=8) ----
      const bool tail = (kv0 + 63 > qw);
      float tmax[2];
#pragma unroll
      for (int qg = 0; qg < 2; ++qg) {
        if (tail) {
          int q = qw + qg * 16 + l15;
#pragma unroll
          for (int st = 0; st < 4; ++st)
#pragma unroll
            for (int r = 0; r < 4; ++r) {
              int key = kv0 + st * 16 + l4 * 4 + r;
              if (key > q) sacc[qg][st][r] = -3.0e38f;
            }
        }
        float a0 = fmaxf(fmaxf(sacc[qg][0][0], sacc[qg][0][1]), fmaxf(sacc[qg][0][2], sacc[qg][0][3]));
        float a1 = fmaxf(fmaxf(sacc[qg][1][0], sacc[qg][1][1]), fmaxf(sacc[qg][1][2], sacc[qg][1][3]));
        float a2 = fmaxf(fmaxf(sacc[qg][2][0], sacc[qg][2][1]), fmaxf(sacc[qg][2][2], sacc[qg][2][3]));
        float a3 = fmaxf(fmaxf(sacc[qg][3][0], sacc[qg][3][1]), fmaxf(sacc[qg][3][2], sacc[qg][3][3]));
        float t = fmaxf(fmaxf(a0, a1), fmaxf(a2, a3));
        t = fmaxf(t, __shfl_xor(t, 16));
        t = fmaxf(t, __shfl_xor(t, 32));
        tmax[qg] = t;
      }
      bool grow = (tmax[0] > m_run[0] + 8.f) || (tmax[1] > m_run[1] + 8.f);
      if (__any(grow)) {
#pragma unroll
        for (int qg = 0; qg < 2; ++qg) {
          float nm = fmaxf(m_run[qg], tmax[qg]);
          float scl = __builtin_amdgcn_exp2f((m_run[qg] - nm) * SC);
          m_run[qg] = nm;
          lp[qg] *= scl;
#pragma unroll
          for (int r = 0; r < 4; ++r) {
            float srow = __shfl(scl, l4 * 4 + r);
#pragma unroll
            for (int df = 0; df < 8; ++df) acc[qg][df][r] *= srow;
          }
        }
      }
#pragma unroll
      for (int qg = 0; qg < 2; ++qg) {
        int q = qg * 16 + l15;
        float ps = 0.f;
#pragma unroll
        for (int st = 0; st < 4; ++st) {
          float p0 = __builtin_amdgcn_exp2f((sacc[qg][st][0] - m_run[qg]) * SC);
          float p1 = __builtin_amdgcn_exp2f((sacc[qg][st][1] - m_run[qg]) * SC);
          float p2 = __builtin_amdgcn_exp2f((sacc[qg][st][2] - m_run[qg]) * SC);
          float p3 = __builtin_amdgcn_exp2f((sacc[qg][st][3] - m_run[qg]) * SC);
          ps += (p0 + p1) + (p2 + p3);
          unsigned w0 = (unsigned)f2bf(p0) | ((unsigned)f2bf(p1) << 16);
          unsigned w1 = (unsigned)f2bf(p2) | ((unsigned)f2bf(p3) << 16);
          int kw0 = st * 8 + l4 * 2;
          Pl[w][q * 32 + (kw0 ^ ((q & 7) << 2))] = w0;
          Pl[w][q * 32 + ((kw0 + 1) ^ ((q & 7) << 2))] = w1;
        }
        lp[qg] += ps;
      }
      // ---- O += P V ----
      __builtin_amdgcn_s_setprio(1);
#pragma unroll
      for (int ks2 = 0; ks2 < 2; ++ks2) {
        int kwb = ks2 * 16 + l4 * 4;
        bf16x8 pa0 = *(const bf16x8*)&Pl[w][l15 * 32 + (kwb ^ ((l15 & 7) << 2))];
        bf16x8 pa1 = *(const bf16x8*)&Pl[w][(16 + l15) * 32 + (kwb ^ ((l15 & 7) << 2))];
#pragma unroll
        for (int df = 0; df < 8; ++df) {
          int dh = df * 16 + l15;
          int sv = ((dh >> 3) ^ dh) & 7;
          bf16x8 vb = *(const bf16x8*)&Vt[cur][dh * 64 + ((ks2 * 32 + l4 * 8) ^ (sv << 3))];
          acc[0][df] = __builtin_amdgcn_mfma_f32_16x16x32_bf16(pa0, vb, acc[0][df], 0, 0, 0);
          acc[1][df] = __builtin_amdgcn_mfma_f32_16x16x32_bf16(pa1, vb, acc[1][df], 0, 0, 0);
        }
      }
      __builtin_amdgcn_s_setprio(0);
    }
  }

#pragma unroll
  for (int qg = 0; qg < 2; ++qg) {
    float t = lp[qg];
    t += __shfl_xor(t, 16);
    t += __shfl_xor(t, 32);
    float linv = 1.0f / t;
#pragma unroll
    for (int r = 0; r < 4; ++r) {
      float lrow = __shfl(linv, l4 * 4 + r);
      int row = qw + qg * 16 + l4 * 4 + r;
#pragma unroll
      for (int df = 0; df < 8; ++df)
        O[baseO + (size_t)row * D_MODEL + df * 16 + l15] = f2bf(acc[qg][df][r] * lrow);
    }
  }
}

// ---------------- launch ----------------
extern "C" void kernel_launch(void* const* d_in, const int* in_sizes, int n_in,
                              void* d_out, int out_size, void* d_ws, size_t ws_size,
                              hipStream_t stream) {
  const float* x  = (const float*)d_in[0];
  const float* Wq = (const float*)d_in[1];
  const float* Wk = (const float*)d_in[2];
  const float* Wv = (const float*)d_in[3];
  const float* Wo = (const float*)d_in[4];
  const float* bo = (const float*)d_in[5];
  float* out = (float*)d_out;

  unsigned short* ws = (unsigned short*)d_ws;
  const size_t XSZ = (size_t)MTOT * D_MODEL;      // 16,777,216
  const size_t WSZ = (size_t)D_MODEL * D_MODEL;   // 4,194,304
  unsigned short* xb   = ws;                       // also reused as attn-out
  unsigned short* Wcat = xb + XSZ;                 // [6144][2048] = Wq|Wk|Wv rows
  unsigned short* Wob  = Wcat + 3 * WSZ;
  unsigned short* QKV  = Wob + WSZ;                // [8192][6144]
  unsigned short* AOb  = xb;

  // fused conversions: x (8192 blocks) + 4 weights (2048 each) = 16384 blocks
  cvt_all_k<<<16384, 256, 0, stream>>>(x, Wq, Wk, Wv, Wo, xb, Wcat, Wob);

  // fused QKV projection: [8192,2048] x [6144,2048]^T -> [8192,6144]
  dim3 gq(MTOT / 256, LDQ / 256);   // 32 x 24 = 768 blocks
  gemm256<true, false><<<gq, 512, 0, stream>>>(xb, Wcat, QKV, nullptr, MTOT, LDQ, D_MODEL);

  dim3 ga(SEQ / 128, BATCH * NH);   // 16 x 64
  attn_k<<<ga, 256, 0, stream>>>(QKV, QKV + 2048, QKV + 4096, AOb);

  // output projection: [8192,2048] x [2048,2048]^T -> fp32 + bias
  dim3 gg(MTOT / 256, D_MODEL / 256);  // 32 x 8 = 256 blocks
  gemm256<false, true><<<gg, 512, 0, stream>>>(AOb, Wob, out, bo, MTOT, D_MODEL, D_MODEL);
}